// Round 1
// baseline (142.712 us; speedup 1.0000x reference)
//
#include <hip/hip_runtime.h>
#include <hip/hip_bf16.h>
#include <cmath>

#define BZ 8
#define PZ 8192
#define FZ 768
#define FI 256
#define M_TOTAL (BZ * PZ)   // 65536
#define BM 128
#define BN 128
#define BK 64
#define NKT (FZ / BK)       // 12

typedef __bf16 bf16_t;
typedef __bf16 bf16x8 __attribute__((ext_vector_type(8)));
typedef float f32x4 __attribute__((ext_vector_type(4)));

// ---------------- pack V_w / U_w into pair-interleaved bf16 ----------------
// packed row pr = 32*j + 16*u + r  ->  (u ? U_w : V_w)[16*j + r]
// so any aligned 32-col span of the GEMM N dimension holds a V 16-col
// fragment (even frag) and its matching U 16-col fragment (odd frag).
__global__ void pack_weights(const float* __restrict__ Vw,
                             const float* __restrict__ Uw,
                             bf16_t* __restrict__ Wc) {
    int pr = blockIdx.x;                 // 0..511
    int j = pr >> 5, u = (pr >> 4) & 1, r = pr & 15;
    int o = j * 16 + r;                  // original output index 0..255
    const float* src = (u ? Uw : Vw) + (size_t)o * FZ;
    for (int k = threadIdx.x; k < FZ; k += blockDim.x)
        Wc[(size_t)pr * FZ + k] = (bf16_t)src[k];
}

// ---------------- fused GEMM + gate + w-reduce -> partial logits ----------------
// grid: (65536/128) m-tiles * 4 n-tiles = 2048 blocks, 512 threads (8 waves 4Mx2N)
__global__ __launch_bounds__(512, 2)
void gemm_gate(const float* __restrict__ x, const bf16_t* __restrict__ Wc,
               const float* __restrict__ Vb, const float* __restrict__ Ub,
               const float* __restrict__ ww, float* __restrict__ part) {
    __shared__ bf16_t As[2][BM * BK] __attribute__((aligned(16)));
    __shared__ bf16_t Bs[2][BN * BK] __attribute__((aligned(16)));

    const int bid = blockIdx.x;
    const int mt = bid >> 2, nb = bid & 3;
    const int tid = threadIdx.x;
    const int l = tid & 63, w = tid >> 6;
    const int wm = w >> 1, wn = w & 1;      // 4 M-waves x 2 N-waves
    const int row0 = mt * BM;
    const int pcb = nb * BN;                // packed-col base of this n-tile

    f32x4 acc[2][4] = {};

    // staging: tile = rows x 8 slots of 8 bf16 (16B). XOR swizzle: phys = logical ^ (row&7)
    auto stage = [&](int buf, int t) {
        int k0 = t * BK;
        #pragma unroll
        for (int i = 0; i < 2; ++i) {
            int s = tid + i * 512;          // 0..1023
            int row = s >> 3, ls = s & 7;
            int ps = ls ^ (row & 7);
            // A: fp32 global -> cvt -> LDS (swizzled write)
            const float* gp = x + (size_t)(row0 + row) * FZ + k0 + ls * 8;
            float4 f0 = *(const float4*)gp;
            float4 f1 = *(const float4*)(gp + 4);
            bf16x8 va;
            va[0] = (bf16_t)f0.x; va[1] = (bf16_t)f0.y; va[2] = (bf16_t)f0.z; va[3] = (bf16_t)f0.w;
            va[4] = (bf16_t)f1.x; va[5] = (bf16_t)f1.y; va[6] = (bf16_t)f1.z; va[7] = (bf16_t)f1.w;
            *(bf16x8*)&As[buf][row * BK + ps * 8] = va;
            // B: bf16 global (packed weights) -> LDS (swizzled write)
            const bf16_t* gb = Wc + (size_t)(pcb + row) * FZ + k0 + ls * 8;
            bf16x8 vb = *(const bf16x8*)gb;
            *(bf16x8*)&Bs[buf][row * BK + ps * 8] = vb;
        }
    };

    stage(0, 0);
    __syncthreads();

    for (int t = 0; t < NKT; ++t) {
        int cur = t & 1;
        if (t + 1 < NKT) stage(cur ^ 1, t + 1);   // prefetch into other buffer
        #pragma unroll
        for (int kk = 0; kk < 2; ++kk) {
            bf16x8 af[2], bf[4];
            int lsr = kk * 4 + (l >> 4);
            #pragma unroll
            for (int m = 0; m < 2; ++m) {
                int row = wm * 32 + m * 16 + (l & 15);
                af[m] = *(bf16x8*)&As[cur][row * BK + (lsr ^ (row & 7)) * 8];
            }
            #pragma unroll
            for (int n = 0; n < 4; ++n) {
                int row = wn * 64 + n * 16 + (l & 15);
                bf[n] = *(bf16x8*)&Bs[cur][row * BK + (lsr ^ (row & 7)) * 8];
            }
            #pragma unroll
            for (int m = 0; m < 2; ++m)
                #pragma unroll
                for (int n = 0; n < 4; ++n)
                    acc[m][n] = __builtin_amdgcn_mfma_f32_16x16x32_bf16(af[m], bf[n], acc[m][n], 0, 0, 0);
        }
        __syncthreads();
    }

    // ---- epilogue: gate + reduce over this wave's 64 output pairs ----
    const int c = l & 15;
    const int base = pcb + wn * 64;          // packed-col base of wave tile
    float vb0[2], ub0[2], wv0[2];
    #pragma unroll
    for (int p = 0; p < 2; ++p) {
        int o = ((base + 32 * p) >> 5) * 16 + c;   // original output index
        vb0[p] = Vb[o]; ub0[p] = Ub[o]; wv0[p] = ww[o];
    }
    const int slot = nb * 2 + wn;            // 0..7 disjoint partial slots
    #pragma unroll
    for (int m = 0; m < 2; ++m) {
        #pragma unroll
        for (int e = 0; e < 4; ++e) {
            float partial = 0.f;
            #pragma unroll
            for (int p = 0; p < 2; ++p) {
                float v = tanhf(acc[m][2 * p][e] + vb0[p]);
                float uu = 1.f / (1.f + expf(-(acc[m][2 * p + 1][e] + ub0[p])));
                partial += v * uu * wv0[p];
            }
            partial += __shfl_xor(partial, 1);
            partial += __shfl_xor(partial, 2);
            partial += __shfl_xor(partial, 4);
            partial += __shfl_xor(partial, 8);
            if (c == 0) {
                int rowg = row0 + wm * 32 + m * 16 + (l >> 4) * 4 + e;
                part[(size_t)slot * M_TOTAL + rowg] = partial;
            }
        }
    }
}

// ---------------- per-bag masked softmax ----------------
__global__ __launch_bounds__(1024)
void softmax_kernel(const float* __restrict__ part, const int* __restrict__ nonpad,
                    float* __restrict__ out) {
    __shared__ float satt[PZ];
    __shared__ float red[16];
    int b = blockIdx.x;
    int np = nonpad[b];
    int tid = threadIdx.x;

    for (int p = tid; p < PZ; p += 1024) {
        float s = 0.f;
        #pragma unroll
        for (int q = 0; q < 8; ++q) s += part[(size_t)q * M_TOTAL + b * PZ + p];
        satt[p] = s;
    }
    __syncthreads();

    float m = -3.4e38f;
    for (int p = tid; p < np; p += 1024) m = fmaxf(m, satt[p]);
    #pragma unroll
    for (int off = 32; off; off >>= 1) m = fmaxf(m, __shfl_xor(m, off));
    if ((tid & 63) == 0) red[tid >> 6] = m;
    __syncthreads();
    m = red[0];
    #pragma unroll
    for (int i = 1; i < 16; ++i) m = fmaxf(m, red[i]);
    __syncthreads();

    float sum = 0.f;
    for (int p = tid; p < np; p += 1024) sum += expf(satt[p] - m);
    #pragma unroll
    for (int off = 32; off; off >>= 1) sum += __shfl_xor(sum, off);
    if ((tid & 63) == 0) red[tid >> 6] = sum;
    __syncthreads();
    float S = red[0];
    #pragma unroll
    for (int i = 1; i < 16; ++i) S += red[i];
    float inv = 1.f / S;

    for (int p = tid; p < PZ; p += 1024)
        out[b * PZ + p] = (p < np) ? expf(satt[p] - m) * inv : 0.f;
}

extern "C" void kernel_launch(void* const* d_in, const int* in_sizes, int n_in,
                              void* d_out, int out_size, void* d_ws, size_t ws_size,
                              hipStream_t stream) {
    const float* x   = (const float*)d_in[0];
    const int* nonpad = (const int*)d_in[1];
    const float* V_w = (const float*)d_in[2];
    const float* V_b = (const float*)d_in[3];
    const float* U_w = (const float*)d_in[4];
    const float* U_b = (const float*)d_in[5];
    const float* w_w = (const float*)d_in[6];
    // d_in[7] = w_b: uniform logit shift -> softmax-invariant, unused.

    bf16_t* Wc  = (bf16_t*)d_ws;                                  // 512*768*2 = 768 KB
    float* part = (float*)((char*)d_ws + (size_t)512 * FZ * 2);   // 8*65536*4 = 2 MB
    float* out  = (float*)d_out;

    pack_weights<<<512, 128, 0, stream>>>(V_w, U_w, Wc);
    gemm_gate<<<2048, 512, 0, stream>>>(x, Wc, V_b, U_b, w_w, part);
    softmax_kernel<<<8, 1024, 0, stream>>>(part, nonpad, out);
}

// Round 2
// 135.565 us; speedup vs baseline: 1.0527x; 1.0527x over previous
//
#include <hip/hip_runtime.h>
#include <hip/hip_bf16.h>
#include <cmath>

#define BZ 8
#define PZ 8192
#define FZ 768
#define FI 256
#define M_TOTAL (BZ * PZ)   // 65536
#define BM 128
#define BN 128
#define BK 64
#define NKT (FZ / BK)       // 12

typedef __bf16 bf16_t;
typedef __bf16 bf16x8 __attribute__((ext_vector_type(8)));
typedef float f32x16 __attribute__((ext_vector_type(16)));

// ---------------- pack V_w / U_w into pair-interleaved bf16 ----------------
// packed row pr = 32*j + 16*u + r  ->  (u ? U_w : V_w)[16*j + r]
__global__ void pack_weights(const float* __restrict__ Vw,
                             const float* __restrict__ Uw,
                             bf16_t* __restrict__ Wc) {
    int pr = blockIdx.x;                 // 0..511
    int j = pr >> 5, u = (pr >> 4) & 1, r = pr & 15;
    int o = j * 16 + r;                  // original output index 0..255
    const float* src = (u ? Uw : Vw) + (size_t)o * FZ;
    for (int k = threadIdx.x; k < FZ; k += blockDim.x)
        Wc[(size_t)pr * FZ + k] = (bf16_t)src[k];
}

// ---------------- fused GEMM + gate + w-reduce -> partial logits ----------------
// 2048 blocks, 256 threads (4 waves, 2M x 2N, wave tile 64x64 of 32x32 frags)
__global__ __launch_bounds__(256, 3)
void gemm_gate(const float* __restrict__ x, const bf16_t* __restrict__ Wc,
               const float* __restrict__ Vb, const float* __restrict__ Ub,
               const float* __restrict__ ww, float* __restrict__ part) {
    __shared__ bf16_t As[BM * BK] __attribute__((aligned(16)));   // 16 KB, swizzled
    __shared__ bf16_t Bs[BN * BK] __attribute__((aligned(16)));   // 16 KB, swizzled

    // XCD-aware remap: the 4 n-blocks of one m-tile share bid%8 (same XCD L2)
    const int bid = blockIdx.x;
    const int nb = (bid >> 3) & 3;
    const int mt = (bid & 7) | ((bid >> 5) << 3);    // 0..511
    const int tid = threadIdx.x;
    const int l = tid & 63, wv = tid >> 6;           // lane, wave 0..3
    const int wm = wv >> 1, wn = wv & 1;             // 2M x 2N waves
    const int row0 = mt * BM;
    const int pcb = nb * BN;                         // packed-col base

    f32x16 acc[2][2] = {};
    float4 areg[8];                                  // A staging: 32 fp32/thread

    // --- A: issue global fp32 loads for tile t (coalesced: lane strides 32B) ---
    auto loadA = [&](int t) {
        int k0 = t * BK;
        #pragma unroll
        for (int i = 0; i < 4; ++i) {
            int row = i * 32 + (tid >> 3);           // 0..127
            const float* gp = x + (size_t)(row0 + row) * FZ + k0 + (tid & 7) * 8;
            areg[2 * i]     = *(const float4*)gp;
            areg[2 * i + 1] = *(const float4*)(gp + 4);
        }
    };
    // --- A: cvt + swizzled LDS write (slot q -> phys q^(row&7)) ---
    auto writeA = [&]() {
        #pragma unroll
        for (int i = 0; i < 4; ++i) {
            int row = i * 32 + (tid >> 3);
            int q = tid & 7;
            float4 f0 = areg[2 * i], f1 = areg[2 * i + 1];
            bf16x8 v;
            v[0] = (bf16_t)f0.x; v[1] = (bf16_t)f0.y; v[2] = (bf16_t)f0.z; v[3] = (bf16_t)f0.w;
            v[4] = (bf16_t)f1.x; v[5] = (bf16_t)f1.y; v[6] = (bf16_t)f1.z; v[7] = (bf16_t)f1.w;
            *(bf16x8*)&As[row * BK + (q ^ (row & 7)) * 8] = v;
        }
    };
    // --- B: global_load_lds, linear LDS dest + inverse-swizzled global source ---
    auto loadB = [&](int t) {
        int k0 = t * BK;
        #pragma unroll
        for (int cc = 0; cc < 4; ++cc) {
            int chunk = cc * 4 + wv;                 // 16 chunks of 1024 B
            int row = chunk * 8 + (l >> 3);          // LDS row this lane fills
            int ps = l & 7;                          // phys slot this lane fills
            const bf16_t* gp = Wc + (size_t)(pcb + row) * FZ + k0 + (ps ^ (row & 7)) * 8;
            bf16_t* lp = &Bs[chunk * 512];           // wave-uniform base (+lane*16 in HW)
            __builtin_amdgcn_global_load_lds(
                (const __attribute__((address_space(1))) void*)gp,
                (__attribute__((address_space(3))) void*)lp, 16, 0, 0);
        }
    };

    loadA(0);
    for (int t = 0; t < NKT; ++t) {
        __syncthreads();                 // everyone done reading previous tile
        writeA();                        // waits on areg loads (vmcnt), writes tile t
        loadB(t);                        // async -> LDS
        if (t + 1 < NKT) loadA(t + 1);   // issue next A loads into freed regs
        __syncthreads();                 // drains vm+lgkm: tile t ready
        #pragma unroll
        for (int kk = 0; kk < 4; ++kk) {
            int ks = kk * 2 + (l >> 5);  // 16B k-slot for this lane
            bf16x8 af[2], bfr[2];
            #pragma unroll
            for (int fm = 0; fm < 2; ++fm) {
                int row = wm * 64 + fm * 32 + (l & 31);
                af[fm] = *(bf16x8*)&As[row * BK + (ks ^ (row & 7)) * 8];
            }
            #pragma unroll
            for (int fn = 0; fn < 2; ++fn) {
                int row = wn * 64 + fn * 32 + (l & 31);
                bfr[fn] = *(bf16x8*)&Bs[row * BK + (ks ^ (row & 7)) * 8];
            }
            #pragma unroll
            for (int fm = 0; fm < 2; ++fm)
                #pragma unroll
                for (int fn = 0; fn < 2; ++fn)
                    acc[fm][fn] = __builtin_amdgcn_mfma_f32_32x32x16_bf16(
                        af[fm], bfr[fn], acc[fm][fn], 0, 0, 0);
        }
    }

    // ---- epilogue: gate + reduce ----
    // C/D 32x32 layout: col = l&31, row = (e&3) + 8*(e>>2) + 4*(l>>5)
    const int col = l & 31;
    const int u = col >> 4;               // 0: V-half lane, 1: U-half lane
    float bias[2], wcf[2];
    #pragma unroll
    for (int fn = 0; fn < 2; ++fn) {
        int o = ((pcb + wn * 64 + fn * 32) >> 5) * 16 + (col & 15);
        bias[fn] = u ? Ub[o] : Vb[o];
        wcf[fn] = ww[o];
    }
    const int slot = nb * 2 + wn;         // 8 disjoint partial slots
    #pragma unroll
    for (int fm = 0; fm < 2; ++fm) {
        #pragma unroll
        for (int e = 0; e < 16; ++e) {
            float partial = 0.f;
            #pragma unroll
            for (int fn = 0; fn < 2; ++fn) {
                float z = acc[fm][fn][e] + bias[fn];
                float act = u ? (1.f / (1.f + expf(-z))) : tanhf(z);
                float pact = __shfl_xor(act, 16);     // partner half's activation
                partial += u ? 0.f : act * pact * wcf[fn];
            }
            partial += __shfl_xor(partial, 1);
            partial += __shfl_xor(partial, 2);
            partial += __shfl_xor(partial, 4);
            partial += __shfl_xor(partial, 8);
            if ((l & 31) == 0) {
                int r = row0 + wm * 64 + fm * 32 + (e & 3) + 8 * (e >> 2) + 4 * (l >> 5);
                part[(size_t)slot * M_TOTAL + r] = partial;
            }
        }
    }
}

// ---------------- per-bag masked softmax ----------------
__global__ __launch_bounds__(1024)
void softmax_kernel(const float* __restrict__ part, const int* __restrict__ nonpad,
                    float* __restrict__ out) {
    __shared__ float satt[PZ];
    __shared__ float red[16];
    int b = blockIdx.x;
    int np = nonpad[b];
    int tid = threadIdx.x;

    for (int p = tid; p < PZ; p += 1024) {
        float s = 0.f;
        #pragma unroll
        for (int q = 0; q < 8; ++q) s += part[(size_t)q * M_TOTAL + b * PZ + p];
        satt[p] = s;
    }
    __syncthreads();

    float m = -3.4e38f;
    for (int p = tid; p < np; p += 1024) m = fmaxf(m, satt[p]);
    #pragma unroll
    for (int off = 32; off; off >>= 1) m = fmaxf(m, __shfl_xor(m, off));
    if ((tid & 63) == 0) red[tid >> 6] = m;
    __syncthreads();
    m = red[0];
    #pragma unroll
    for (int i = 1; i < 16; ++i) m = fmaxf(m, red[i]);
    __syncthreads();

    float sum = 0.f;
    for (int p = tid; p < np; p += 1024) sum += expf(satt[p] - m);
    #pragma unroll
    for (int off = 32; off; off >>= 1) sum += __shfl_xor(sum, off);
    if ((tid & 63) == 0) red[tid >> 6] = sum;
    __syncthreads();
    float S = red[0];
    #pragma unroll
    for (int i = 1; i < 16; ++i) S += red[i];
    float inv = 1.f / S;

    for (int p = tid; p < PZ; p += 1024)
        out[b * PZ + p] = (p < np) ? expf(satt[p] - m) * inv : 0.f;
}

extern "C" void kernel_launch(void* const* d_in, const int* in_sizes, int n_in,
                              void* d_out, int out_size, void* d_ws, size_t ws_size,
                              hipStream_t stream) {
    const float* x   = (const float*)d_in[0];
    const int* nonpad = (const int*)d_in[1];
    const float* V_w = (const float*)d_in[2];
    const float* V_b = (const float*)d_in[3];
    const float* U_w = (const float*)d_in[4];
    const float* U_b = (const float*)d_in[5];
    const float* w_w = (const float*)d_in[6];
    // d_in[7] = w_b: uniform logit shift -> softmax-invariant, unused.

    bf16_t* Wc  = (bf16_t*)d_ws;                                  // 768 KB
    float* part = (float*)((char*)d_ws + (size_t)512 * FZ * 2);   // 2 MB
    float* out  = (float*)d_out;

    pack_weights<<<512, 128, 0, stream>>>(V_w, U_w, Wc);
    gemm_gate<<<2048, 256, 0, stream>>>(x, Wc, V_b, U_b, w_w, part);
    softmax_kernel<<<8, 1024, 0, stream>>>(part, nonpad, out);
}